// Round 1
// baseline (818.100 us; speedup 1.0000x reference)
//
#include <hip/hip_runtime.h>
#include <hip/hip_bf16.h>
#include <stdint.h>

// MLA forward: B=2,S=2048,H=2048,NH=16,D=128,LAT=512. Inputs fp32 (R3-proven).
// R10: flash occupancy push. 16 q-rows/wave (was 32) -> persistent regs ~halved;
// Kr read direct from global (head-independent, L2-hot) -> sKr LDS dropped;
// LDS 56KB->36KB. 4 blocks/CU (was 2), __launch_bounds__(256,4) caps VGPR<=128.
// sP XOR-swizzled (old layout: 8-way bank conflict on P writes). setprio around
// MFMA clusters (m191: +4-7% attn). GEMMs: UK|UV|UQ merged N=6144 (unchanged).
typedef __hip_bfloat16 bf16;
typedef __attribute__((ext_vector_type(8))) short s8v;   // 8 x bf16 (4 VGPRs)
typedef __attribute__((ext_vector_type(4))) float f4v;   // MFMA 16x16 accum

__device__ __forceinline__ void gld16(const bf16* g, bf16* l) {
  __builtin_amdgcn_global_load_lds(
      (__attribute__((address_space(1))) unsigned int*)g,
      (__attribute__((address_space(3))) unsigned int*)l, 16, 0, 0);
}

__device__ __forceinline__ f4v mfma16(s8v a, s8v b, f4v c) {
  return __builtin_amdgcn_mfma_f32_16x16x32_bf16(a, b, c, 0, 0, 0);
}

__device__ __forceinline__ unsigned short f2bfu(float f) {
  union { bf16 h; unsigned short u; } cv;
  cv.h = __float2bfloat16(f);
  return cv.u;
}

// sP row swizzle: rw = kch*16 + q (rw<64), row = 8 bf16 (16B). Old banks used:
// {(rw&7)*4..+3} only -> 8-way write conflict. XOR elem bit4 with rw bit3 and
// bit3 with rw bit4: write lanes (l4 varies) land on 4 distinct 16B slots;
// read's l15/l15+8 alias killed. Bijective (XOR sources live at bits 6-8).
__device__ __forceinline__ int pswz(int rw) {
  return (rw << 3) ^ (((rw >> 3) & 1) << 4) ^ (((rw >> 4) & 1) << 3);
}

// ---------------- prep: hs fp32->bf16 + 8 weight transposes + bias concat ----------------
__global__ __launch_bounds__(256) void prep(
    const float* __restrict__ hs, bf16* __restrict__ hsb,
    const float* __restrict__ bdkv, const float* __restrict__ bdq,
    const float* __restrict__ bkr, const float* __restrict__ bqr,
    float* __restrict__ bcat,
    const float* __restrict__ wdkv, bf16* __restrict__ tdkv,
    const float* __restrict__ wdq,  bf16* __restrict__ tdq,
    const float* __restrict__ wkr,  bf16* __restrict__ tkr,
    const float* __restrict__ wqr,  bf16* __restrict__ tqr,
    const float* __restrict__ wuk,  bf16* __restrict__ tuk,
    const float* __restrict__ wuv,  bf16* __restrict__ tuv,
    const float* __restrict__ wuq,  bf16* __restrict__ tuq,
    const float* __restrict__ wo,   bf16* __restrict__ to_) {
  int bid = blockIdx.x;
  int tid = threadIdx.x;
  if (bid < 4096) {
    int i = (bid * 256 + tid) * 8;
    union { s8v v; unsigned short u[8]; } pk;
#pragma unroll
    for (int j = 0; j < 8; j++) pk.u[j] = f2bfu(hs[i + j]);
    *(s8v*)(hsb + i) = pk.v;
    return;
  }
  if (bid == 4096) {
#pragma unroll
    for (int p = 0; p < 5; p++) {
      int i = tid + p * 256;
      float v;
      if (i < 512)       v = bdkv[i];
      else if (i < 1024) v = bdq[i - 512];
      else if (i < 1152) v = bkr[i - 1024];
      else               v = bqr[i - 1152];
      bcat[i] = v;
    }
    return;
  }
  bid -= 4097;
  const float* src; bf16* dst; int R, C;
  if      (bid < 1024) { src = wdkv; dst = tdkv; R = 2048; C = 512;  }
  else if (bid < 2048) { src = wdq;  dst = tdq;  R = 2048; C = 512;  bid -= 1024; }
  else if (bid < 2304) { src = wkr;  dst = tkr;  R = 2048; C = 128;  bid -= 2048; }
  else if (bid < 2560) { src = wqr;  dst = tqr;  R = 2048; C = 128;  bid -= 2304; }
  else if (bid < 3584) { src = wuk;  dst = tuk;  R = 512;  C = 2048; bid -= 2560; }
  else if (bid < 4608) { src = wuv;  dst = tuv;  R = 512;  C = 2048; bid -= 3584; }
  else if (bid < 5632) { src = wuq;  dst = tuq;  R = 512;  C = 2048; bid -= 4608; }
  else                 { src = wo;   dst = to_;  R = 2048; C = 2048; bid -= 5632; }
  __shared__ float t[32][33];
  int C32 = C >> 5;
  int bx = bid % C32, by = bid / C32;
  int tx = tid & 31, ty = tid >> 5;
  int c0 = bx * 32, r0 = by * 32;
#pragma unroll
  for (int i = 0; i < 32; i += 8)
    t[ty + i][tx] = src[(size_t)(r0 + ty + i) * C + c0 + tx];
  __syncthreads();
#pragma unroll
  for (int i = 0; i < 32; i += 8)
    dst[(size_t)(c0 + ty + i) * R + r0 + tx] = __float2bfloat16(t[tx][ty + i]);
}

// ---------------- rope (both k and q in one launch) ----------------
__global__ void rope_kernel(const bf16* __restrict__ inK, bf16* __restrict__ outK,
                            const bf16* __restrict__ inQ, bf16* __restrict__ outQ) {
  const bf16* in = (blockIdx.y == 0) ? inK : inQ;
  bf16* out = (blockIdx.y == 0) ? outK : outQ;
  int row = blockIdx.x;       // b*2048 + s
  int d = threadIdx.x;        // 0..63
  int pos = row & 2047;
  float x1 = __bfloat162float(in[(size_t)row * 128 + d]);
  float x2 = __bfloat162float(in[(size_t)row * 128 + 64 + d]);
  float inv = exp2f(-(float)d * (13.287712379549449f / 64.0f));  // 10000^(-d/64)
  float ang = (float)pos * inv;
  float sn = sinf(ang), cs = cosf(ang);
  out[(size_t)row * 128 + d]      = __float2bfloat16(x1 * cs - x2 * sn);
  out[(size_t)row * 128 + 64 + d] = __float2bfloat16(x1 * sn + x2 * cs);
}

// ---------------- GEMM: C(MxN) = A(MxK) @ Bt(NxK)^T + bias ----------------
// m97 structure: 128x128 tile, BK=32, 4 waves (2x2), global_load_lds w=16.
template <int MODE>
__global__ __launch_bounds__(256) void gemm_bt(
    const bf16* __restrict__ A, const bf16* __restrict__ A2,
    const bf16* __restrict__ Bt,
    const float* __restrict__ b0, const float* __restrict__ b1,
    const float* __restrict__ b2,
    void* __restrict__ C0, void* __restrict__ C1,
    void* __restrict__ C2, void* __restrict__ C3,
    int M, int N, int K) {
  __shared__ bf16 sA[128 * 32];
  __shared__ bf16 sB[128 * 32];
  const int tid = threadIdx.x, lane = tid & 63, wid = tid >> 6;
  const int l15 = lane & 15, l4 = lane >> 4;
  const int m0 = blockIdx.y * 128, n0 = blockIdx.x * 128;
  const int wm = (wid >> 1) * 64, wn = (wid & 1) * 64;
  f4v acc[4][4] = {};
  const bf16* Ause = (MODE == 2 && n0 >= 4096) ? A2 : A;
  const bf16* gA = Ause + (size_t)m0 * K;
  const bf16* gB = Bt + (size_t)n0 * K;
  const int row = tid >> 2, col = (tid & 3) * 8;
  for (int k0 = 0; k0 < K; k0 += 32) {
    gld16(gA + (size_t)row * K + k0 + col,        sA + tid * 8);
    gld16(gA + (size_t)(row + 64) * K + k0 + col, sA + (tid + 256) * 8);
    gld16(gB + (size_t)row * K + k0 + col,        sB + tid * 8);
    gld16(gB + (size_t)(row + 64) * K + k0 + col, sB + (tid + 256) * 8);
    __syncthreads();
    s8v a[4], b[4];
#pragma unroll
    for (int i = 0; i < 4; i++) a[i] = *(const s8v*)(sA + (wm + i * 16 + l15) * 32 + l4 * 8);
#pragma unroll
    for (int j = 0; j < 4; j++) b[j] = *(const s8v*)(sB + (wn + j * 16 + l15) * 32 + l4 * 8);
#pragma unroll
    for (int i = 0; i < 4; i++)
#pragma unroll
      for (int j = 0; j < 4; j++) acc[i][j] = mfma16(a[i], b[j], acc[i][j]);
    __syncthreads();
  }
  // epilogue. C/D layout: row = l4*4+g, col = l15 (within 16x16 tile)
#pragma unroll
  for (int j = 0; j < 4; j++) {
    const int nb = n0 + wn + j * 16;      // 16-col tile base (uniform per j)
    const int n = nb + l15;
    if (MODE == 3) {
      const float bv = b0[n];
#pragma unroll
      for (int i = 0; i < 4; i++) {
        size_t mb = m0 + wm + i * 16 + l4 * 4;
#pragma unroll
        for (int g = 0; g < 4; g++)
          ((float*)C0)[(mb + g) * (size_t)N + n] = acc[i][j][g] + bv;
      }
    } else if (MODE == 1) {
      const float bv = b0[n];  // 1280-entry concat
      bf16* dst; int stride, nc;
      if (nb < 512)       { dst = (bf16*)C0; stride = 512; nc = n; }
      else if (nb < 1024) { dst = (bf16*)C1; stride = 512; nc = n - 512; }
      else if (nb < 1152) { dst = (bf16*)C2; stride = 128; nc = n - 1024; }
      else                { dst = (bf16*)C3; stride = 128; nc = n - 1152; }
#pragma unroll
      for (int i = 0; i < 4; i++) {
        size_t mb = m0 + wm + i * 16 + l4 * 4;
#pragma unroll
        for (int g = 0; g < 4; g++)
          dst[(mb + g) * (size_t)stride + nc] = __float2bfloat16(acc[i][j][g] + bv);
      }
    } else {  // MODE 2: UK (k_c) | UV (vT) | UQ (q_c)
      if (nb < 2048) {
        const float bv = b0[n];
        bf16* dst = (bf16*)C0;
#pragma unroll
        for (int i = 0; i < 4; i++) {
          size_t mb = m0 + wm + i * 16 + l4 * 4;
#pragma unroll
          for (int g = 0; g < 4; g++)
            dst[(mb + g) * (size_t)2048 + n] = __float2bfloat16(acc[i][j][g] + bv);
        }
      } else if (nb < 4096) {
        const float bv = b1[n - 2048];
        bf16* dst = (bf16*)C1;
        int nn = n - 2048, hh = nn >> 7, dd = nn & 127;
#pragma unroll
        for (int i = 0; i < 4; i++) {
          int m = m0 + wm + i * 16 + l4 * 4;
          int bb = m >> 11, ss = m & 2047;
          unsigned int lo = f2bfu(acc[i][j][0] + bv) | ((unsigned int)f2bfu(acc[i][j][1] + bv) << 16);
          unsigned int hi = f2bfu(acc[i][j][2] + bv) | ((unsigned int)f2bfu(acc[i][j][3] + bv) << 16);
          size_t dstoff = ((size_t)(bb * 16 + hh) * 128 + dd) * 2048 + ss;
          uint2 pk; pk.x = lo; pk.y = hi;
          *reinterpret_cast<uint2*>(dst + dstoff) = pk;
        }
      } else {
        const float bv = b2[n - 4096];
        bf16* dst = (bf16*)C2;
        int nn = n - 4096;
#pragma unroll
        for (int i = 0; i < 4; i++) {
          size_t mb = m0 + wm + i * 16 + l4 * 4;
#pragma unroll
          for (int g = 0; g < 4; g++)
            dst[(mb + g) * (size_t)2048 + nn] = __float2bfloat16(acc[i][j][g] + bv);
        }
      }
    }
  }
}

// ---------------- flash attention (no-max softmax, double-buffered) ----------------
// grid (S/64, B*NH), 256 thr (4 waves; wave owns 16 q-rows). BN=32 keys/iter.
// LDS: sK[2] = [dchunk(16)][key(32)][8] 8KB ea, sVT[2] = [kch(4)][d(128)][8]
// 8KB ea, sP 4KB -> 36KB total -> 4 blocks/CU. Kr NOT staged: head-independent
// (16 heads share it) -> L2-hot, read B-fragments direct from global. Those
// loads are issued BEFORE stage() so their vmcnt wait (in-order retirement)
// doesn't drain the cross-barrier prefetch. Persistent regs: qcf+qrf 32 +
// oacc 32 -> fits <=128 unified VGPR for 4 waves/SIMD.
__global__ __launch_bounds__(256, 4) void flash_attn(
    const bf16* __restrict__ Qc, const bf16* __restrict__ Kc,
    const bf16* __restrict__ Qr, const bf16* __restrict__ Kr,
    const bf16* __restrict__ VT, const int* __restrict__ amask,
    bf16* __restrict__ ctx) {
  const int S = 2048, H = 2048, D = 128;
  __shared__ bf16 sK[2][16 * 32 * 8];
  __shared__ bf16 sVT[2][4 * 128 * 8];
  __shared__ bf16 sP[4][4 * 16 * 8];  // per-wave P: swizzled [kchunk(4)][q(16)][8]

  const int tid = threadIdx.x, lane = tid & 63, wid = tid >> 6;
  const int l15 = lane & 15, l4 = lane >> 4;
  const int qt = blockIdx.x, bh = blockIdx.y;
  const int b = bh >> 4, h = bh & 15;
  const size_t bS = (size_t)b * S;
  const int q0 = qt * 64 + wid * 16;

  // Q fragments in registers (A-operand: m=l15 -> q=q0+l15, k=t*32+l4*8+j)
  s8v qcf[4], qrf[4];
  {
    size_t qrow = bS + q0 + l15;
    const bf16* pc = Qc + qrow * H + h * D + l4 * 8;
    const bf16* pr = Qr + qrow * D + l4 * 8;
#pragma unroll
    for (int t = 0; t < 4; t++) {
      qcf[t] = *(const s8v*)(pc + t * 32);
      qrf[t] = *(const s8v*)(pr + t * 32);
    }
  }

  f4v oacc[8] = {};
  float lsum[4] = {};
  const float scl = 0.08838834764831845f;  // 1/sqrt(128)

  auto stage = [&](int buf, int kv) {
#pragma unroll
    for (int p = 0; p < 2; p++) {
      int idx = tid + p * 256;
      int key = (idx & 31), dch = (idx >> 5);
      gld16(Kc + (bS + kv + key) * H + h * D + dch * 8, sK[buf] + idx * 8);
      int d = (idx & 127), kch = (idx >> 7);
      gld16(VT + ((size_t)bh * D + d) * S + kv + kch * 8, sVT[buf] + idx * 8);
    }
  };

  stage(0, 0);
  for (int it = 0; it < 64; ++it) {
    const int cur = it & 1;
    const int kv0 = it * 32;
    __syncthreads();                       // drains cur's loads; prev reads done

    // Kr B-fragments from global (n=key=c*16+l15, kchunk=t*4+l4). Issued first:
    // oldest in the vmcnt queue, so waiting for them leaves stage() in flight.
    s8v krf[2][4];
#pragma unroll
    for (int c = 0; c < 2; c++)
#pragma unroll
      for (int t = 0; t < 4; t++)
        krf[c][t] = *(const s8v*)(Kr + (bS + kv0 + c * 16 + l15) * (size_t)D + (t * 4 + l4) * 8);

    if (it + 1 < 64) stage(cur ^ 1, (it + 1) * 32);  // prefetch across compute

    int mv[2];
#pragma unroll
    for (int c = 0; c < 2; c++) mv[c] = amask[bS + kv0 + c * 16 + l15];

    // S = Qc.Kc^T + Qr.Kr^T. All Kc MFMAs first (LDS, ready post-barrier) so
    // the krf global-load latency hides under them.
    f4v sc[2] = {};
    __builtin_amdgcn_s_setprio(1);
#pragma unroll
    for (int c = 0; c < 2; c++)
#pragma unroll
      for (int t = 0; t < 4; t++) {
        s8v kf = *(const s8v*)(sK[cur] + ((t * 4 + l4) * 32 + c * 16 + l15) * 8);
        sc[c] = mfma16(qcf[t], kf, sc[c]);
      }
#pragma unroll
    for (int c = 0; c < 2; c++)
#pragma unroll
      for (int t = 0; t < 4; t++)
        sc[c] = mfma16(qrf[t], krf[c][t], sc[c]);
    __builtin_amdgcn_s_setprio(0);

    // no-max softmax: p = exp(s*scl) (0 where masked); per-lane partial sums
#pragma unroll
    for (int g = 0; g < 4; g++) {
      int qr_ = l4 * 4 + g;
#pragma unroll
      for (int c = 0; c < 2; c++) {
        float p = (mv[c] == 0) ? 0.f : __expf(sc[c][g] * scl);
        lsum[g] += p;
        int kch = 2 * c + (l15 >> 3);
        sP[wid][pswz(kch * 16 + qr_) + (l15 & 7)] = __float2bfloat16(p);
      }
    }
    // same-wave ds_write -> ds_read ordering
    asm volatile("s_waitcnt lgkmcnt(0)" ::: "memory");

    // O += P @ V  (P A-frag: m=l15 -> q, kchunk=l4; V B-frag: n=c*16+l15)
    {
      s8v pf = *(const s8v*)(sP[wid] + pswz(l4 * 16 + l15));
      __builtin_amdgcn_s_setprio(1);
#pragma unroll
      for (int c = 0; c < 8; c++) {
        s8v vf = *(const s8v*)(sVT[cur] + (l4 * 128 + c * 16 + l15) * 8);
        oacc[c] = mfma16(pf, vf, oacc[c]);
      }
      __builtin_amdgcn_s_setprio(0);
    }
  }

  // finalize row sums: reduce over the 16 lanes (l15) holding each row's cols
#pragma unroll
  for (int g = 0; g < 4; g++) {
    float s = lsum[g];
#pragma unroll
    for (int off = 8; off; off >>= 1) s += __shfl_xor(s, off, 64);
    lsum[g] = 1.0f / s;
  }

  // normalize + store ctx (B,S,H)
#pragma unroll
  for (int c = 0; c < 8; c++) {
#pragma unroll
    for (int g = 0; g < 4; g++) {
      int qrow = q0 + l4 * 4 + g;
      float val = oacc[c][g] * lsum[g];
      ctx[(bS + qrow) * H + h * D + c * 16 + l15] = __float2bfloat16(val);
    }
  }
}

// ---------------- launch ----------------
extern "C" void kernel_launch(void* const* d_in, const int* in_sizes, int n_in,
                              void* d_out, int out_size, void* d_ws, size_t ws_size,
                              hipStream_t stream) {
  const float* hs    = (const float*)d_in[0];
  const int*   amask = (const int*)d_in[1];
  const float* W_DKV = (const float*)d_in[2];  const float* b_DKV = (const float*)d_in[3];
  const float* W_DQ  = (const float*)d_in[4];  const float* b_DQ  = (const float*)d_in[5];
  const float* W_UK  = (const float*)d_in[6];  const float* b_UK  = (const float*)d_in[7];
  const float* W_UV  = (const float*)d_in[8];  const float* b_UV  = (const float*)d_in[9];
  const float* W_UQ  = (const float*)d_in[10]; const float* b_UQ  = (const float*)d_in[11];
  const float* W_KR  = (const float*)d_in[12]; const float* b_KR  = (const float*)d_in[13];
  const float* W_QR  = (const float*)d_in[14]; const float* b_QR  = (const float*)d_in[15];
  const float* W_O   = (const float*)d_in[16]; const float* b_O   = (const float*)d_in[17];

  char* wsb = (char*)d_ws;
  size_t off = 0;
  auto allocB = [&](size_t bytes) {
    void* p = wsb + off; off = (off + bytes + 255) & ~(size_t)255; return p;
  };
  float* bcat  = (float*)allocB(1280 * 4);
  bf16* hsb    = (bf16*)allocB((size_t)4096 * 2048 * 2);
  bf16* wt_dkv = (bf16*)allocB((size_t)512 * 2048 * 2);
  bf16* wt_dq  = (bf16*)allocB((size_t)512 * 2048 * 2);
  bf16* wt_kr  = (bf16*)allocB((size_t)128 * 2048 * 2);
  bf16* wt_qr  = (bf16*)allocB((size_t)128 * 2048 * 2);
  // wt_uk|wt_uv|wt_uq MUST stay contiguous (single Bt for the merged GEMM):
  bf16* wt_uk  = (bf16*)allocB((size_t)2048 * 512 * 2);
  bf16* wt_uv  = (bf16*)allocB((size_t)2048 * 512 * 2);
  bf16* wt_uq  = (bf16*)allocB((size_t)2048 * 512 * 2);
  bf16* wt_o   = (bf16*)allocB((size_t)2048 * 2048 * 2);
  bf16* c_kv   = (bf16*)allocB((size_t)4096 * 512 * 2);
  bf16* c_q    = (bf16*)allocB((size_t)4096 * 512 * 2);
  bf16* krl    = (bf16*)allocB((size_t)4096 * 128 * 2);
  bf16* qrl    = (bf16*)allocB((size_t)4096 * 128 * 2);
  bf16* k_r    = (bf16*)allocB((size_t)4096 * 128 * 2);
  bf16* q_r    = (bf16*)allocB((size_t)4096 * 128 * 2);
  bf16* k_c    = (bf16*)allocB((size_t)4096 * 2048 * 2);
  bf16* q_c    = (bf16*)allocB((size_t)4096 * 2048 * 2);
  bf16* vT     = (bf16*)allocB((size_t)4096 * 2048 * 2);
  bf16* ctx    = (bf16*)allocB((size_t)4096 * 2048 * 2);
  (void)wt_uv; (void)wt_uq;

  // one-shot ingest: 4096 hs-convert + 1 bias-concat + 9728 transpose tiles
  prep<<<13825, 256, 0, stream>>>(hs, hsb,
      b_DKV, b_DQ, b_KR, b_QR, bcat,
      W_DKV, wt_dkv, W_DQ, wt_dq, W_KR, wt_kr, W_QR, wt_qr,
      W_UK, wt_uk, W_UV, wt_uv, W_UQ, wt_uq, W_O, wt_o);

  // fused projections: N = 512|512|128|128 = 1280, K = 2048
  gemm_bt<1><<<dim3(10, 32), 256, 0, stream>>>(
      hsb, nullptr, wt_dkv, bcat, nullptr, nullptr,
      c_kv, c_q, krl, qrl, 4096, 1280, 2048);
  rope_kernel<<<dim3(4096, 2), 64, 0, stream>>>(krl, k_r, qrl, q_r);

  // merged UK|UV|UQ: N = 2048*3 = 6144, K = 512 (A = c_kv for n<4096, c_q above)
  gemm_bt<2><<<dim3(48, 32), 256, 0, stream>>>(
      c_kv, c_q, wt_uk, b_UK, b_UV, b_UQ,
      k_c, vT, q_c, nullptr, 4096, 6144, 512);

  // attention: grid (2048/64, 32) = 1024 blocks = 4/CU exactly
  flash_attn<<<dim3(32, 32), 256, 0, stream>>>(q_c, k_c, q_r, k_r, vT, amask, ctx);

  // output projection (fp32 out)
  gemm_bt<3><<<dim3(16, 32), 256, 0, stream>>>(
      ctx, nullptr, wt_o, b_O, nullptr, nullptr,
      d_out, nullptr, nullptr, nullptr, 4096, 2048, 2048);
}

// Round 2
// 454.165 us; speedup vs baseline: 1.8013x; 1.8013x over previous
//
#include <hip/hip_runtime.h>
#include <hip/hip_bf16.h>
#include <stdint.h>

// MLA forward: B=2,S=2048,H=2048,NH=16,D=128,LAT=512. Inputs fp32 (R3-proven).
// R11: revert to R9 structure (R10's 4-blk/CU push spilled: VGPR 64 + 24MB
// scratch writes -> 3x regression). Single change vs R9: SWAPPED QK^T
// (mfma(K,Q)) -> P is lane-local; sP buffer + 16 ds_write_b16 + lgkmcnt(0)
// drain + P re-reads replaced by 16 ds_bpermute + 8 selects. LDS 56->48KB,
// R9's 4.19M bank-conflict cycles (scalar sP writes) eliminated.
typedef __hip_bfloat16 bf16;
typedef __attribute__((ext_vector_type(8))) short s8v;   // 8 x bf16 (4 VGPRs)
typedef __attribute__((ext_vector_type(4))) float f4v;   // MFMA 16x16 accum

__device__ __forceinline__ void gld16(const bf16* g, bf16* l) {
  __builtin_amdgcn_global_load_lds(
      (__attribute__((address_space(1))) unsigned int*)g,
      (__attribute__((address_space(3))) unsigned int*)l, 16, 0, 0);
}

__device__ __forceinline__ f4v mfma16(s8v a, s8v b, f4v c) {
  return __builtin_amdgcn_mfma_f32_16x16x32_bf16(a, b, c, 0, 0, 0);
}

__device__ __forceinline__ unsigned short f2bfu(float f) {
  union { bf16 h; unsigned short u; } cv;
  cv.h = __float2bfloat16(f);
  return cv.u;
}

// ---------------- prep: hs fp32->bf16 + 8 weight transposes + bias concat ----------------
__global__ __launch_bounds__(256) void prep(
    const float* __restrict__ hs, bf16* __restrict__ hsb,
    const float* __restrict__ bdkv, const float* __restrict__ bdq,
    const float* __restrict__ bkr, const float* __restrict__ bqr,
    float* __restrict__ bcat,
    const float* __restrict__ wdkv, bf16* __restrict__ tdkv,
    const float* __restrict__ wdq,  bf16* __restrict__ tdq,
    const float* __restrict__ wkr,  bf16* __restrict__ tkr,
    const float* __restrict__ wqr,  bf16* __restrict__ tqr,
    const float* __restrict__ wuk,  bf16* __restrict__ tuk,
    const float* __restrict__ wuv,  bf16* __restrict__ tuv,
    const float* __restrict__ wuq,  bf16* __restrict__ tuq,
    const float* __restrict__ wo,   bf16* __restrict__ to_) {
  int bid = blockIdx.x;
  int tid = threadIdx.x;
  if (bid < 4096) {
    int i = (bid * 256 + tid) * 8;
    union { s8v v; unsigned short u[8]; } pk;
#pragma unroll
    for (int j = 0; j < 8; j++) pk.u[j] = f2bfu(hs[i + j]);
    *(s8v*)(hsb + i) = pk.v;
    return;
  }
  if (bid == 4096) {
#pragma unroll
    for (int p = 0; p < 5; p++) {
      int i = tid + p * 256;
      float v;
      if (i < 512)       v = bdkv[i];
      else if (i < 1024) v = bdq[i - 512];
      else if (i < 1152) v = bkr[i - 1024];
      else               v = bqr[i - 1152];
      bcat[i] = v;
    }
    return;
  }
  bid -= 4097;
  const float* src; bf16* dst; int R, C;
  if      (bid < 1024) { src = wdkv; dst = tdkv; R = 2048; C = 512;  }
  else if (bid < 2048) { src = wdq;  dst = tdq;  R = 2048; C = 512;  bid -= 1024; }
  else if (bid < 2304) { src = wkr;  dst = tkr;  R = 2048; C = 128;  bid -= 2048; }
  else if (bid < 2560) { src = wqr;  dst = tqr;  R = 2048; C = 128;  bid -= 2304; }
  else if (bid < 3584) { src = wuk;  dst = tuk;  R = 512;  C = 2048; bid -= 2560; }
  else if (bid < 4608) { src = wuv;  dst = tuv;  R = 512;  C = 2048; bid -= 3584; }
  else if (bid < 5632) { src = wuq;  dst = tuq;  R = 512;  C = 2048; bid -= 4608; }
  else                 { src = wo;   dst = to_;  R = 2048; C = 2048; bid -= 5632; }
  __shared__ float t[32][33];
  int C32 = C >> 5;
  int bx = bid % C32, by = bid / C32;
  int tx = tid & 31, ty = tid >> 5;
  int c0 = bx * 32, r0 = by * 32;
#pragma unroll
  for (int i = 0; i < 32; i += 8)
    t[ty + i][tx] = src[(size_t)(r0 + ty + i) * C + c0 + tx];
  __syncthreads();
#pragma unroll
  for (int i = 0; i < 32; i += 8)
    dst[(size_t)(c0 + ty + i) * R + r0 + tx] = __float2bfloat16(t[tx][ty + i]);
}

// ---------------- rope (both k and q in one launch) ----------------
__global__ void rope_kernel(const bf16* __restrict__ inK, bf16* __restrict__ outK,
                            const bf16* __restrict__ inQ, bf16* __restrict__ outQ) {
  const bf16* in = (blockIdx.y == 0) ? inK : inQ;
  bf16* out = (blockIdx.y == 0) ? outK : outQ;
  int row = blockIdx.x;       // b*2048 + s
  int d = threadIdx.x;        // 0..63
  int pos = row & 2047;
  float x1 = __bfloat162float(in[(size_t)row * 128 + d]);
  float x2 = __bfloat162float(in[(size_t)row * 128 + 64 + d]);
  float inv = exp2f(-(float)d * (13.287712379549449f / 64.0f));  // 10000^(-d/64)
  float ang = (float)pos * inv;
  float sn = sinf(ang), cs = cosf(ang);
  out[(size_t)row * 128 + d]      = __float2bfloat16(x1 * cs - x2 * sn);
  out[(size_t)row * 128 + 64 + d] = __float2bfloat16(x1 * sn + x2 * cs);
}

// ---------------- GEMM: C(MxN) = A(MxK) @ Bt(NxK)^T + bias ----------------
// m97 structure: 128x128 tile, BK=32, 4 waves (2x2), global_load_lds w=16.
template <int MODE>
__global__ __launch_bounds__(256) void gemm_bt(
    const bf16* __restrict__ A, const bf16* __restrict__ A2,
    const bf16* __restrict__ Bt,
    const float* __restrict__ b0, const float* __restrict__ b1,
    const float* __restrict__ b2,
    void* __restrict__ C0, void* __restrict__ C1,
    void* __restrict__ C2, void* __restrict__ C3,
    int M, int N, int K) {
  __shared__ bf16 sA[128 * 32];
  __shared__ bf16 sB[128 * 32];
  const int tid = threadIdx.x, lane = tid & 63, wid = tid >> 6;
  const int l15 = lane & 15, l4 = lane >> 4;
  const int m0 = blockIdx.y * 128, n0 = blockIdx.x * 128;
  const int wm = (wid >> 1) * 64, wn = (wid & 1) * 64;
  f4v acc[4][4] = {};
  const bf16* Ause = (MODE == 2 && n0 >= 4096) ? A2 : A;
  const bf16* gA = Ause + (size_t)m0 * K;
  const bf16* gB = Bt + (size_t)n0 * K;
  const int row = tid >> 2, col = (tid & 3) * 8;
  for (int k0 = 0; k0 < K; k0 += 32) {
    gld16(gA + (size_t)row * K + k0 + col,        sA + tid * 8);
    gld16(gA + (size_t)(row + 64) * K + k0 + col, sA + (tid + 256) * 8);
    gld16(gB + (size_t)row * K + k0 + col,        sB + tid * 8);
    gld16(gB + (size_t)(row + 64) * K + k0 + col, sB + (tid + 256) * 8);
    __syncthreads();
    s8v a[4], b[4];
#pragma unroll
    for (int i = 0; i < 4; i++) a[i] = *(const s8v*)(sA + (wm + i * 16 + l15) * 32 + l4 * 8);
#pragma unroll
    for (int j = 0; j < 4; j++) b[j] = *(const s8v*)(sB + (wn + j * 16 + l15) * 32 + l4 * 8);
#pragma unroll
    for (int i = 0; i < 4; i++)
#pragma unroll
      for (int j = 0; j < 4; j++) acc[i][j] = mfma16(a[i], b[j], acc[i][j]);
    __syncthreads();
  }
  // epilogue. C/D layout: row = l4*4+g, col = l15 (within 16x16 tile)
#pragma unroll
  for (int j = 0; j < 4; j++) {
    const int nb = n0 + wn + j * 16;      // 16-col tile base (uniform per j)
    const int n = nb + l15;
    if (MODE == 3) {
      const float bv = b0[n];
#pragma unroll
      for (int i = 0; i < 4; i++) {
        size_t mb = m0 + wm + i * 16 + l4 * 4;
#pragma unroll
        for (int g = 0; g < 4; g++)
          ((float*)C0)[(mb + g) * (size_t)N + n] = acc[i][j][g] + bv;
      }
    } else if (MODE == 1) {
      const float bv = b0[n];  // 1280-entry concat
      bf16* dst; int stride, nc;
      if (nb < 512)       { dst = (bf16*)C0; stride = 512; nc = n; }
      else if (nb < 1024) { dst = (bf16*)C1; stride = 512; nc = n - 512; }
      else if (nb < 1152) { dst = (bf16*)C2; stride = 128; nc = n - 1024; }
      else                { dst = (bf16*)C3; stride = 128; nc = n - 1152; }
#pragma unroll
      for (int i = 0; i < 4; i++) {
        size_t mb = m0 + wm + i * 16 + l4 * 4;
#pragma unroll
        for (int g = 0; g < 4; g++)
          dst[(mb + g) * (size_t)stride + nc] = __float2bfloat16(acc[i][j][g] + bv);
      }
    } else {  // MODE 2: UK (k_c) | UV (vT) | UQ (q_c)
      if (nb < 2048) {
        const float bv = b0[n];
        bf16* dst = (bf16*)C0;
#pragma unroll
        for (int i = 0; i < 4; i++) {
          size_t mb = m0 + wm + i * 16 + l4 * 4;
#pragma unroll
          for (int g = 0; g < 4; g++)
            dst[(mb + g) * (size_t)2048 + n] = __float2bfloat16(acc[i][j][g] + bv);
        }
      } else if (nb < 4096) {
        const float bv = b1[n - 2048];
        bf16* dst = (bf16*)C1;
        int nn = n - 2048, hh = nn >> 7, dd = nn & 127;
#pragma unroll
        for (int i = 0; i < 4; i++) {
          int m = m0 + wm + i * 16 + l4 * 4;
          int bb = m >> 11, ss = m & 2047;
          unsigned int lo = f2bfu(acc[i][j][0] + bv) | ((unsigned int)f2bfu(acc[i][j][1] + bv) << 16);
          unsigned int hi = f2bfu(acc[i][j][2] + bv) | ((unsigned int)f2bfu(acc[i][j][3] + bv) << 16);
          size_t dstoff = ((size_t)(bb * 16 + hh) * 128 + dd) * 2048 + ss;
          uint2 pk; pk.x = lo; pk.y = hi;
          *reinterpret_cast<uint2*>(dst + dstoff) = pk;
        }
      } else {
        const float bv = b2[n - 4096];
        bf16* dst = (bf16*)C2;
        int nn = n - 4096;
#pragma unroll
        for (int i = 0; i < 4; i++) {
          size_t mb = m0 + wm + i * 16 + l4 * 4;
#pragma unroll
          for (int g = 0; g < 4; g++)
            dst[(mb + g) * (size_t)2048 + nn] = __float2bfloat16(acc[i][j][g] + bv);
        }
      }
    }
  }
}

// ---------------- flash attention (no-max softmax, swapped QK^T, dbuf) ----------------
// grid (S/128, B*NH), 256 thr (4 waves; wave owns 32 q-rows). BN=32 keys/iter.
// LDS: sK/sKr/sVT[2] 8KB each -> 48KB. One barrier/iter, prefetch in flight
// across compute (R9 scheme). SWAPPED QK: sc = mfma(kf, qf) -> lane holds
// P[key=m*16+l4*4+g][q=r*16+l15]. PV A-frag (q=l15, keys=l4*8+j) assembled
// in-register: dest (l4,w) pulls pk[r][m=l4>>1][w&1] from src lane
// (2*(l4&1)+(w>>1))*16+l15 -> 16 ds_bpermute + 8 cndmask per wave-iter.
// No sP, no scalar ds_writes (R9's 4.19M bank conflicts), no lgkmcnt(0) drain.
__global__ __launch_bounds__(256, 2) void flash_attn(
    const bf16* __restrict__ Qc, const bf16* __restrict__ Kc,
    const bf16* __restrict__ Qr, const bf16* __restrict__ Kr,
    const bf16* __restrict__ VT, const int* __restrict__ amask,
    bf16* __restrict__ ctx) {
  const int S = 2048, H = 2048, D = 128;
  __shared__ bf16 sK[2][16 * 32 * 8];
  __shared__ bf16 sKr[2][16 * 32 * 8];
  __shared__ bf16 sVT[2][4 * 128 * 8];

  const int tid = threadIdx.x, lane = tid & 63, wid = tid >> 6;
  const int l15 = lane & 15, l4 = lane >> 4;
  const int qt = blockIdx.x, bh = blockIdx.y;
  const int b = bh >> 4, h = bh & 15;
  const size_t bS = (size_t)b * S;
  const int q0 = qt * 128 + wid * 32;

  // Q fragments in registers. Layout (A- and B-frag identical for 16x16x32):
  // non-k index = l15 -> q = q0 + r*16 + l15; k = t*32 + l4*8 + j.
  s8v qcf[2][4], qrf[2][4];
#pragma unroll
  for (int r = 0; r < 2; r++) {
    size_t qrow = bS + q0 + r * 16 + l15;
    const bf16* pc = Qc + qrow * H + h * D + l4 * 8;
    const bf16* pr = Qr + qrow * D + l4 * 8;
#pragma unroll
    for (int t = 0; t < 4; t++) {
      qcf[r][t] = *(const s8v*)(pc + t * 32);
      qrf[r][t] = *(const s8v*)(pr + t * 32);
    }
  }

  f4v oacc[2][8] = {};
  float lsum[2] = {};
  const float scl = 0.08838834764831845f;  // 1/sqrt(128)

  auto stage = [&](int buf, int kv) {
#pragma unroll
    for (int p = 0; p < 2; p++) {
      int idx = tid + p * 256;
      int key = (idx & 31), dch = (idx >> 5);
      gld16(Kc + (bS + kv + key) * H + h * D + dch * 8, sK[buf] + idx * 8);
      gld16(Kr + (bS + kv + key) * D + dch * 8, sKr[buf] + idx * 8);
      int d = (idx & 127), kch = (idx >> 7);
      gld16(VT + ((size_t)bh * D + d) * S + kv + kch * 8, sVT[buf] + idx * 8);
    }
  };

  // bpermute source-lane byte addresses (loop-invariant)
  const int ae = ((2 * (l4 & 1)) * 16 + l15) * 4;   // even src lane
  const int ao = ae + 64;                           // odd src lane (+16 lanes)
  const bool mhi = (l4 >= 2);                       // dest wants m=1 packs

  stage(0, 0);
  for (int it = 0; it < 64; ++it) {
    const int cur = it & 1;
    const int kv0 = it * 32;
    __syncthreads();                       // drains cur's loads; prev reads done
    if (it + 1 < 64) stage(cur ^ 1, (it + 1) * 32);  // prefetch across compute

    // mask per key: key = kv0 + m*16 + l4*4 + g (int4-aligned)
    int4 mv[2];
#pragma unroll
    for (int m = 0; m < 2; m++)
      mv[m] = *(const int4*)(amask + bS + kv0 + m * 16 + l4 * 4);

    // S^T = Kc.Qc^T + Kr.Qr^T (swapped): rows=key, cols=q
    f4v sc[2][2] = {};   // [m: key tile][r: q tile]
    __builtin_amdgcn_s_setprio(1);
#pragma unroll
    for (int m = 0; m < 2; m++)
#pragma unroll
      for (int t = 0; t < 4; t++) {
        s8v kf = *(const s8v*)(sK[cur] + ((t * 4 + l4) * 32 + m * 16 + l15) * 8);
        sc[m][0] = mfma16(kf, qcf[0][t], sc[m][0]);
        sc[m][1] = mfma16(kf, qcf[1][t], sc[m][1]);
      }
#pragma unroll
    for (int m = 0; m < 2; m++)
#pragma unroll
      for (int t = 0; t < 4; t++) {
        s8v kf = *(const s8v*)(sKr[cur] + ((t * 4 + l4) * 32 + m * 16 + l15) * 8);
        sc[m][0] = mfma16(kf, qrf[0][t], sc[m][0]);
        sc[m][1] = mfma16(kf, qrf[1][t], sc[m][1]);
      }
    __builtin_amdgcn_s_setprio(0);

    // no-max softmax, packed to bf16 pairs: pk[r][m][w] (w=0: g0|g1, w=1: g2|g3)
    unsigned int pk[2][2][2];
#pragma unroll
    for (int m = 0; m < 2; m++)
#pragma unroll
      for (int r = 0; r < 2; r++) {
        float p0 = mv[m].x ? __expf(sc[m][r][0] * scl) : 0.f;
        float p1 = mv[m].y ? __expf(sc[m][r][1] * scl) : 0.f;
        float p2 = mv[m].z ? __expf(sc[m][r][2] * scl) : 0.f;
        float p3 = mv[m].w ? __expf(sc[m][r][3] * scl) : 0.f;
        lsum[r] += (p0 + p1) + (p2 + p3);
        pk[r][m][0] = (unsigned int)f2bfu(p0) | ((unsigned int)f2bfu(p1) << 16);
        pk[r][m][1] = (unsigned int)f2bfu(p2) | ((unsigned int)f2bfu(p3) << 16);
      }

    // assemble PV A-frags in-register (16 bpermute + 8 select)
    s8v pf[2];
#pragma unroll
    for (int r = 0; r < 2; r++) {
      int a0 = __builtin_amdgcn_ds_bpermute(ae, (int)pk[r][0][0]);
      int b0 = __builtin_amdgcn_ds_bpermute(ae, (int)pk[r][1][0]);
      int a1 = __builtin_amdgcn_ds_bpermute(ae, (int)pk[r][0][1]);
      int b1 = __builtin_amdgcn_ds_bpermute(ae, (int)pk[r][1][1]);
      int a2 = __builtin_amdgcn_ds_bpermute(ao, (int)pk[r][0][0]);
      int b2 = __builtin_amdgcn_ds_bpermute(ao, (int)pk[r][1][0]);
      int a3 = __builtin_amdgcn_ds_bpermute(ao, (int)pk[r][0][1]);
      int b3 = __builtin_amdgcn_ds_bpermute(ao, (int)pk[r][1][1]);
      union { int w[4]; s8v v; } u;
      u.w[0] = mhi ? b0 : a0;
      u.w[1] = mhi ? b1 : a1;
      u.w[2] = mhi ? b2 : a2;
      u.w[3] = mhi ? b3 : a3;
      pf[r] = u.v;
    }

    // O += P @ V  (A: q=l15, k=key=l4*8+j; B: n=d=c*16+l15)
    __builtin_amdgcn_s_setprio(1);
#pragma unroll
    for (int c = 0; c < 8; c++) {
      s8v vf = *(const s8v*)(sVT[cur] + (l4 * 128 + c * 16 + l15) * 8);
      oacc[0][c] = mfma16(pf[0], vf, oacc[0][c]);
      oacc[1][c] = mfma16(pf[1], vf, oacc[1][c]);
    }
    __builtin_amdgcn_s_setprio(0);
  }

  // finalize row sums: lsum[r] covers q=r*16+l15 (partial over this lane's
  // keys) -> reduce across l4 groups, then redistribute to oacc's q=l4*4+g.
  float inv[2][4];
#pragma unroll
  for (int r = 0; r < 2; r++) {
    float s = lsum[r];
    s += __shfl_xor(s, 16, 64);
    s += __shfl_xor(s, 32, 64);
#pragma unroll
    for (int g = 0; g < 4; g++) inv[r][g] = 1.0f / __shfl(s, l4 * 4 + g, 64);
  }

  // normalize + store ctx (B,S,H). oacc row = q = r*16 + l4*4 + g, col = d.
#pragma unroll
  for (int r = 0; r < 2; r++) {
#pragma unroll
    for (int c = 0; c < 8; c++) {
#pragma unroll
      for (int g = 0; g < 4; g++) {
        int qrow = q0 + r * 16 + l4 * 4 + g;
        float val = oacc[r][c][g] * inv[r][g];
        ctx[(bS + qrow) * H + h * D + c * 16 + l15] = __float2bfloat16(val);
      }
    }
  }
}

// ---------------- launch ----------------
extern "C" void kernel_launch(void* const* d_in, const int* in_sizes, int n_in,
                              void* d_out, int out_size, void* d_ws, size_t ws_size,
                              hipStream_t stream) {
  const float* hs    = (const float*)d_in[0];
  const int*   amask = (const int*)d_in[1];
  const float* W_DKV = (const float*)d_in[2];  const float* b_DKV = (const float*)d_in[3];
  const float* W_DQ  = (const float*)d_in[4];  const float* b_DQ  = (const float*)d_in[5];
  const float* W_UK  = (const float*)d_in[6];  const float* b_UK  = (const float*)d_in[7];
  const float* W_UV  = (const float*)d_in[8];  const float* b_UV  = (const float*)d_in[9];
  const float* W_UQ  = (const float*)d_in[10]; const float* b_UQ  = (const float*)d_in[11];
  const float* W_KR  = (const float*)d_in[12]; const float* b_KR  = (const float*)d_in[13];
  const float* W_QR  = (const float*)d_in[14]; const float* b_QR  = (const float*)d_in[15];
  const float* W_O   = (const float*)d_in[16]; const float* b_O   = (const float*)d_in[17];

  char* wsb = (char*)d_ws;
  size_t off = 0;
  auto allocB = [&](size_t bytes) {
    void* p = wsb + off; off = (off + bytes + 255) & ~(size_t)255; return p;
  };
  float* bcat  = (float*)allocB(1280 * 4);
  bf16* hsb    = (bf16*)allocB((size_t)4096 * 2048 * 2);
  bf16* wt_dkv = (bf16*)allocB((size_t)512 * 2048 * 2);
  bf16* wt_dq  = (bf16*)allocB((size_t)512 * 2048 * 2);
  bf16* wt_kr  = (bf16*)allocB((size_t)128 * 2048 * 2);
  bf16* wt_qr  = (bf16*)allocB((size_t)128 * 2048 * 2);
  // wt_uk|wt_uv|wt_uq MUST stay contiguous (single Bt for the merged GEMM):
  bf16* wt_uk  = (bf16*)allocB((size_t)2048 * 512 * 2);
  bf16* wt_uv  = (bf16*)allocB((size_t)2048 * 512 * 2);
  bf16* wt_uq  = (bf16*)allocB((size_t)2048 * 512 * 2);
  bf16* wt_o   = (bf16*)allocB((size_t)2048 * 2048 * 2);
  bf16* c_kv   = (bf16*)allocB((size_t)4096 * 512 * 2);
  bf16* c_q    = (bf16*)allocB((size_t)4096 * 512 * 2);
  bf16* krl    = (bf16*)allocB((size_t)4096 * 128 * 2);
  bf16* qrl    = (bf16*)allocB((size_t)4096 * 128 * 2);
  bf16* k_r    = (bf16*)allocB((size_t)4096 * 128 * 2);
  bf16* q_r    = (bf16*)allocB((size_t)4096 * 128 * 2);
  bf16* k_c    = (bf16*)allocB((size_t)4096 * 2048 * 2);
  bf16* q_c    = (bf16*)allocB((size_t)4096 * 2048 * 2);
  bf16* vT     = (bf16*)allocB((size_t)4096 * 2048 * 2);
  bf16* ctx    = (bf16*)allocB((size_t)4096 * 2048 * 2);
  (void)wt_uv; (void)wt_uq;

  // one-shot ingest: 4096 hs-convert + 1 bias-concat + 9728 transpose tiles
  prep<<<13825, 256, 0, stream>>>(hs, hsb,
      b_DKV, b_DQ, b_KR, b_QR, bcat,
      W_DKV, wt_dkv, W_DQ, wt_dq, W_KR, wt_kr, W_QR, wt_qr,
      W_UK, wt_uk, W_UV, wt_uv, W_UQ, wt_uq, W_O, wt_o);

  // fused projections: N = 512|512|128|128 = 1280, K = 2048
  gemm_bt<1><<<dim3(10, 32), 256, 0, stream>>>(
      hsb, nullptr, wt_dkv, bcat, nullptr, nullptr,
      c_kv, c_q, krl, qrl, 4096, 1280, 2048);
  rope_kernel<<<dim3(4096, 2), 64, 0, stream>>>(krl, k_r, qrl, q_r);

  // merged UK|UV|UQ: N = 2048*3 = 6144, K = 512 (A = c_kv for n<4096, c_q above)
  gemm_bt<2><<<dim3(48, 32), 256, 0, stream>>>(
      c_kv, c_q, wt_uk, b_UK, b_UV, b_UQ,
      k_c, vT, q_c, nullptr, 4096, 6144, 512);

  // attention: grid (2048/128, 32) = 512 blocks, 2/CU
  flash_attn<<<dim3(16, 32), 256, 0, stream>>>(q_c, k_c, q_r, k_r, vT, amask, ctx);

  // output projection (fp32 out)
  gemm_bt<3><<<dim3(16, 32), 256, 0, stream>>>(
      ctx, nullptr, wt_o, b_O, nullptr, nullptr,
      d_out, nullptr, nullptr, nullptr, 4096, 2048, 2048);
}